// Round 6
// baseline (632.819 us; speedup 1.0000x reference)
//
#include <hip/hip_runtime.h>
#include <hip/hip_fp16.h>

#define NFEAT 5
#define HID 64
#define BSH 8               // dst bucket = dst >> 8  (256 nodes/bucket)
#define BNODES 256
#define NBK2 512            // max buckets (n <= 131072)
#define CHUNK 4096          // edges per bin block
#define ECAPMAX 12288       // per-bucket slice cap (LDS rank array bound)

// persistent layer23 phase-sweep geometry
#define L23_BLOCKS 2048
#define L23_TPB 256
#define L23_WAVES (L23_BLOCKS * L23_TPB / 64)   // 8192 waves, all co-resident
#define NPW 13                                  // nodes per wave (covers 106496)
#define NPH 7                                   // src phases
#define PHW2 16384                              // src window = 2 MB of g1h

// ---- init per-bucket allocator cursors to static bases ----
__global__ void k_binit(int* bcur, int ecap) {
    bcur[threadIdx.x] = threadIdx.x * ecap;
}

// ---- bin edges by dst-bucket into statically-capped bucket slices.
//      packed 4B entries: src | (dst&255)<<17 ; ONE LDS-atomic round; int4 loads ----
__global__ __launch_bounds__(256) void
k_bin(const int* __restrict__ src, const int* __restrict__ dst,
      int* bcur, unsigned* __restrict__ binned, int E) {
    __shared__ unsigned stg[CHUNK];          // 16 KB
    __shared__ unsigned short bkt[CHUNK];    // 8 KB
    __shared__ int hist[NBK2], base[NBK2], gb[NBK2];
    __shared__ int tmp[256];
    int t = threadIdx.x;
    int e0 = blockIdx.x * CHUNK;
    int cc = E - e0; if (cc > CHUNK) cc = CHUNK;
    hist[t] = 0; hist[t + 256] = 0;
    __syncthreads();
    unsigned me[16]; int mb[16]; unsigned short mr[16];
    const int4* src4 = (const int4*)(src + e0);
    const int4* dst4 = (const int4*)(dst + e0);
#pragma unroll
    for (int k = 0; k < 4; ++k) {
        int i4 = k * 256 + t;          // int4 index within chunk
        int ib = i4 * 4;               // edge offset within chunk
        int ss[4], dd[4];
        bool any = false;
        if (e0 + ib + 3 < E) {
            int4 s4 = src4[i4], d4 = dst4[i4];
            ss[0]=s4.x; ss[1]=s4.y; ss[2]=s4.z; ss[3]=s4.w;
            dd[0]=d4.x; dd[1]=d4.y; dd[2]=d4.z; dd[3]=d4.w;
            any = true;
#pragma unroll
            for (int j = 0; j < 4; ++j) mb[k*4+j] = 0;
        } else {
#pragma unroll
            for (int j = 0; j < 4; ++j) {
                if (e0 + ib + j < E) { ss[j]=src[e0+ib+j]; dd[j]=dst[e0+ib+j]; any=true; mb[k*4+j]=0; }
                else mb[k*4+j] = -1;
            }
        }
        if (any) {
#pragma unroll
            for (int j = 0; j < 4; ++j) {
                int idx = k * 4 + j;
                if (mb[idx] >= 0) {
                    mb[idx] = dd[j] >> BSH;
                    me[idx] = (unsigned)ss[j] | ((unsigned)(dd[j] & (BNODES - 1)) << 17);
                    mr[idx] = (unsigned short)atomicAdd(&hist[mb[idx]], 1);
                }
            }
        }
    }
    __syncthreads();
    // exclusive scan over 512 bins (2/thread)
    int c0 = hist[2*t], c1 = hist[2*t + 1];
    int s = c0 + c1;
    tmp[t] = s;
    __syncthreads();
    for (int off = 1; off < 256; off <<= 1) {
        int a = (t >= off) ? tmp[t - off] : 0;
        __syncthreads();
        tmp[t] += a;
        __syncthreads();
    }
    int excl = tmp[t] - s;
    base[2*t]     = excl;
    base[2*t + 1] = excl + c0;
    gb[2*t]     = c0 ? atomicAdd(&bcur[2*t], c0) : 0;
    gb[2*t + 1] = c1 ? atomicAdd(&bcur[2*t + 1], c1) : 0;
    __syncthreads();
#pragma unroll
    for (int k = 0; k < 16; ++k)
        if (mb[k] >= 0) {
            int p = base[mb[k]] + mr[k];
            stg[p] = me[k];
            bkt[p] = (unsigned short)mb[k];
        }
    __syncthreads();
#pragma unroll
    for (int k = 0; k < 16; ++k) {
        int p = k * 256 + t;
        if (p < cc) {
            int b = bkt[p];
            binned[gb[b] + (p - base[b])] = stg[p];   // coalesced bucket runs
        }
    }
}

// ---- per-bucket counting sort by local dst (node-major, contiguous rows):
//      pass-1 atomic returns final rank (LDS u16) -> pass-2 has NO atomics.
//      emits csr (padded layout), rpN/rpE, dis, xs = dis*x padded to 8 floats ----
__global__ __launch_bounds__(256) void
k_sort(const unsigned* __restrict__ binned, const int* __restrict__ bcur,
       const float* __restrict__ x, int* __restrict__ rpN, int* __restrict__ rpE,
       int* __restrict__ csr, float* __restrict__ dis, float* __restrict__ xs,
       int n, int ecap) {
    __shared__ unsigned short rank[ECAPMAX];   // 24 KB
    __shared__ int hist[BNODES];
    __shared__ int cur[BNODES];
    __shared__ int tmp[256];
    int t = threadIdx.x, b = blockIdx.x;
    int e0 = b * ecap;
    int cnt = bcur[b] - e0;           // edges in this bucket
    if (cnt > ecap) cnt = ecap;
    int v0 = b << BSH;
    int nv = n - v0; if (nv > BNODES) nv = BNODES;
    hist[t] = 0;
    __syncthreads();
    for (int i = t; i < cnt; i += 256) {
        int vl = binned[e0 + i] >> 17;
        rank[i] = (unsigned short)atomicAdd(&hist[vl], 1);
    }
    __syncthreads();
    // degree -> dis ; xs = dis * x (padded to 8 floats); one node/thread
    if (t < nv) {
        int v = v0 + t;
        float dv = rsqrtf((float)hist[t] + 1.0f);
        dis[v] = dv;
        const float* xr = x + (size_t)v * NFEAT;
        float* xw = xs + (size_t)v * 8;
        xw[0] = dv * xr[0]; xw[1] = dv * xr[1]; xw[2] = dv * xr[2];
        xw[3] = dv * xr[3]; xw[4] = dv * xr[4];
        xw[5] = 0.f; xw[6] = 0.f; xw[7] = 0.f;
    }
    // exclusive scan of 256 bins (1/thread)
    int c = hist[t];
    tmp[t] = c;
    __syncthreads();
    for (int off = 1; off < 256; off <<= 1) {
        int a = (t >= off) ? tmp[t - off] : 0;
        __syncthreads();
        tmp[t] += a;
        __syncthreads();
    }
    int excl = e0 + tmp[t] - c;       // absolute csr position
    cur[t] = excl;
    if (t < nv) { rpN[v0 + t] = excl; rpE[v0 + t] = excl + c; }
    __syncthreads();
    for (int i = t; i < cnt; i += 256) {
        unsigned e = binned[e0 + i];
        int vl = e >> 17;
        csr[cur[vl] + rank[i]] = (int)(e & 0x1FFFF);
    }
}

// ---- layer 1: wave/node + in-register bitonic src-sort of the row, PLUS
//      per-node phase-cut emission: cut16[ph-1][v] = absolute csr index of
//      first edge with src >= ph*16384 (ph=1..6). Phase 0 start = rpN,
//      phase 6 end = rpE. k_layer23's persistent waves use these to walk
//      all rows through the same 2 MB g1h window per phase WITHOUT any
//      runtime peeking (r2's serialization). deg>64 rows: unsorted, all
//      edges assigned to the last phase (correct; locality loss only). ----
__global__ __launch_bounds__(256) void
k_layer1(const int* __restrict__ rpN, const int* __restrict__ rpE,
         int* __restrict__ csr, int* __restrict__ cut16,
         const float* __restrict__ xs, const float* __restrict__ dis,
         const float* __restrict__ W1, const float* __restrict__ b1,
         __half* __restrict__ g1h, int n) {
    int wave = (blockIdx.x * blockDim.x + threadIdx.x) >> 6;
    int lane = threadIdx.x & 63;
    if (wave >= n) return;
    int v = wave;
    int r0 = rpN[v], r1 = rpE[v];
    int cnt = r1 - r0;
    float a0 = 0.f, a1 = 0.f, a2 = 0.f, a3 = 0.f, a4 = 0.f;
    if (cnt <= 64) {
        int key = (lane < cnt) ? csr[r0 + lane] : 0x7FFFFFFF;
        // 64-lane bitonic sort (21 shfl_xor compare-exchange steps)
#pragma unroll
        for (int k = 2; k <= 64; k <<= 1) {
#pragma unroll
            for (int j = k >> 1; j > 0; j >>= 1) {
                int o = __shfl_xor(key, j, 64);
                bool keepmin = (((lane & j) == 0) == ((lane & k) == 0));
                int mn = key < o ? key : o;
                int mx = key > o ? key : o;
                key = keepmin ? mn : mx;
            }
        }
        // phase cuts: #edges with src < ph*16384 (sentinels 0x7FFFFFFF excluded)
        int c1_ = __popcll(__ballot(key < 1 * PHW2));
        int c2_ = __popcll(__ballot(key < 2 * PHW2));
        int c3_ = __popcll(__ballot(key < 3 * PHW2));
        int c4_ = __popcll(__ballot(key < 4 * PHW2));
        int c5_ = __popcll(__ballot(key < 5 * PHW2));
        int c6_ = __popcll(__ballot(key < 6 * PHW2));
        if (lane >= 1 && lane <= 6) {
            int cc = lane == 1 ? c1_ : lane == 2 ? c2_ : lane == 3 ? c3_ :
                     lane == 4 ? c4_ : lane == 5 ? c5_ : c6_;
            cut16[(lane - 1) * n + v] = r0 + cc;
        }
        if (lane < cnt) {
            csr[r0 + lane] = key;                 // persist sorted row
            const float4* q = (const float4*)(xs + (size_t)key * 8);
            float4 qa = q[0], qb = q[1];
            a0 = qa.x; a1 = qa.y; a2 = qa.z; a3 = qa.w; a4 = qb.x;
        }
    } else {
        if (lane >= 1 && lane <= 6) cut16[(lane - 1) * n + v] = r0;  // all in last phase
        for (int j = r0 + lane; j < r1; j += 64) {
            const float4* q = (const float4*)(xs + (size_t)csr[j] * 8);
            float4 qa = q[0], qb = q[1];
            a0 += qa.x; a1 += qa.y; a2 += qa.z; a3 += qa.w; a4 += qb.x;
        }
    }
#pragma unroll
    for (int m = 32; m > 0; m >>= 1) {
        a0 += __shfl_xor(a0, m, 64); a1 += __shfl_xor(a1, m, 64);
        a2 += __shfl_xor(a2, m, 64); a3 += __shfl_xor(a3, m, 64);
        a4 += __shfl_xor(a4, m, 64);
    }
    float dv = dis[v];
    const float* pv = xs + (size_t)v * 8;   // already dis[v]*x[v]
    a0 = dv * (a0 + pv[0]); a1 = dv * (a1 + pv[1]); a2 = dv * (a2 + pv[2]);
    a3 = dv * (a3 + pv[3]); a4 = dv * (a4 + pv[4]);
    int c = lane;
    float h = b1[c] + a0 * W1[c] + a1 * W1[64 + c] + a2 * W1[128 + c]
            + a3 * W1[192 + c] + a4 * W1[256 + c];
    g1h[(size_t)v * HID + c] = __float2half(dv * fmaxf(h, 0.0f));
}

// ---- layer 2+3: persistent phase-sweep gather with PRECOMPUTED cuts.
//      8192 co-resident waves (2048 blk x 256 thr, <=64 VGPR, 8 wv/SIMD),
//      13 nodes/wave, 13 fp32 accumulators. 7 phases of 16384 srcs (2 MB
//      g1h window -> per-XCD L2-resident). Per (node,phase): window bounds
//      come from cut16 (NO runtime peek/ballot — r2's killer); the inner
//      loop is a clamped group-of-8 (idx=min(j+k,b-1), masked add): 8
//      INDEPENDENT g1h loads in flight — r0's proven MLP shape. Clamped
//      extras are same-address L2 hits. csr reads are nontemporal so the
//      streamed index traffic doesn't evict the g1h window. ----
__global__ __launch_bounds__(L23_TPB, 8) void
k_layer23(const int* __restrict__ rpN, const int* __restrict__ rpE,
          const int* __restrict__ cut16, const int* __restrict__ csr,
          const __half* __restrict__ g1h, const float* __restrict__ dis,
          const float* __restrict__ W2, const float* __restrict__ b2,
          const float* __restrict__ W3, float* __restrict__ svs, int n) {
    __shared__ float W2s[HID * HID];
    for (int i = threadIdx.x; i < HID * HID; i += L23_TPB) W2s[i] = W2[i];
    __syncthreads();
    int wv   = (blockIdx.x * L23_TPB + threadIdx.x) >> 6;
    int lane = threadIdx.x & 63;
    int v0 = wv * NPW;

    float acc[NPW];     // statically indexed only
#pragma unroll
    for (int i = 0; i < NPW; ++i) {
        int v = v0 + i;
        acc[i] = (v < n) ? __half2float(g1h[((size_t)v << 6) + lane]) : 0.f;  // self
    }

    for (int ph = 0; ph < NPH; ++ph) {
        // batch-load this wave's 13 window bounds (lanes 0..12), shfl-broadcast
        int sv_ = 0, ev_ = 0;
        int vL = v0 + lane;
        if (lane < NPW && vL < n) {
            sv_ = (ph == 0)       ? rpN[vL] : cut16[(ph - 1) * n + vL];
            ev_ = (ph == NPH - 1) ? rpE[vL] : cut16[ph * n + vL];
        }
#pragma unroll
        for (int i = 0; i < NPW; ++i) {
            int a = __shfl(sv_, i, 64);
            int b = __shfl(ev_, i, 64);
            for (int j = a; j < b; j += 8) {
                float t[8];
#pragma unroll
                for (int k = 0; k < 8; ++k) {
                    int idx = (j + k < b) ? (j + k) : (b - 1);
                    int s = __builtin_nontemporal_load(&csr[idx]);
                    t[k] = __half2float(g1h[((size_t)s << 6) + lane]);
                }
#pragma unroll
                for (int k = 0; k < 8; ++k)
                    if (j + k < b) acc[i] += t[k];
            }
        }
    }

    // epilogue: W2 shfl-GEMM + relu + W3 dot per node
    for (int i = 0; i < NPW; ++i) {     // runtime loop; acc picked by select
        int v = v0 + i;
        if (v >= n) break;
        float a = acc[0];
#pragma unroll
        for (int t = 1; t < NPW; ++t) if (i == t) a = acc[t];
        float dv = dis[v];
        a *= dv;                                   // agg2[v, lane]
        float outv = b2[lane];
#pragma unroll
        for (int k = 0; k < HID; ++k)
            outv = fmaf(__shfl(a, k, 64), W2s[(k << 6) + lane], outv);
        outv = fmaxf(outv, 0.0f);
        float val = outv * W3[lane];
#pragma unroll
        for (int m = 32; m > 0; m >>= 1) val += __shfl_xor(val, m, 64);
        if (lane == 0) svs[v] = dv * val;          // pre-scaled for output gather
    }

    // safety tail (dead for n <= L23_WAVES*NPW = 106496)
    for (int v = L23_WAVES * NPW + wv; v < n; v += L23_WAVES) {
        int r0 = rpN[v], r1 = rpE[v];
        float a = __half2float(g1h[((size_t)v << 6) + lane]);
        for (int j = r0; j < r1; ++j)
            a += __half2float(g1h[((size_t)csr[j] << 6) + lane]);
        float dv = dis[v];
        a *= dv;
        float outv = b2[lane];
#pragma unroll
        for (int k = 0; k < HID; ++k)
            outv = fmaf(__shfl(a, k, 64), W2s[(k << 6) + lane], outv);
        outv = fmaxf(outv, 0.0f);
        float val = outv * W3[lane];
#pragma unroll
        for (int m = 32; m > 0; m >>= 1) val += __shfl_xor(val, m, 64);
        if (lane == 0) svs[v] = dv * val;
    }
}

// ---- output: wave/node scalar gather over contiguous row ----
__global__ __launch_bounds__(256) void
k_out(const int* __restrict__ rpN, const int* __restrict__ rpE,
      const int* __restrict__ csr, const float* __restrict__ svs,
      const float* __restrict__ dis, const float* __restrict__ b3,
      float* __restrict__ out, int n) {
    int wave = (blockIdx.x * blockDim.x + threadIdx.x) >> 6;
    int lane = threadIdx.x & 63;
    if (wave >= n) return;
    int v = wave;
    int r0 = rpN[v], r1 = rpE[v];
    float acc = (lane == 0) ? svs[v] : 0.f;        // self term
    for (int j = r0 + lane; j < r1; j += 64) acc += svs[csr[j]];
#pragma unroll
    for (int m = 32; m > 0; m >>= 1) acc += __shfl_xor(acc, m, 64);
    if (lane == 0) out[v] = b3[0] + dis[v] * acc;
}

extern "C" void kernel_launch(void* const* d_in, const int* in_sizes, int n_in,
                              void* d_out, int out_size, void* d_ws, size_t ws_size,
                              hipStream_t stream) {
    const float* x  = (const float*)d_in[0];
    const int*   ei = (const int*)d_in[1];
    const float* W1 = (const float*)d_in[2];
    const float* b1 = (const float*)d_in[3];
    const float* W2 = (const float*)d_in[4];
    const float* b2 = (const float*)d_in[5];
    const float* W3 = (const float*)d_in[6];
    const float* b3 = (const float*)d_in[7];
    float* out = (float*)d_out;

    const int n = out_size;           // 100000
    const int E = in_sizes[1] / 2;    // 3200000
    const int* src = ei;
    const int* dst = ei + E;

    const int nbk = (n + BNODES - 1) / BNODES;    // 391 buckets
    int ecap = E / nbk;
    ecap += ecap / 8 + 1024;                      // ~+25% headroom (>>20 sigma)
    if (ecap > ECAPMAX) ecap = ECAPMAX;

    // ws layout (int units):
    // bcur[512] | rpN[n] rpE[n] | dis[n] svs[n]
    // | csr[nbk*ecap] | binned[uint nbk*ecap] (g1h aliases binned) | xs[8n floats]
    // | cut16[6n ints]
    int*      bcur   = (int*)d_ws;
    int*      rpN    = bcur + 512;
    int*      rpE    = rpN + n;
    float*    dis    = (float*)(rpE + n);
    float*    svs    = dis + n;
    int*      csr    = (int*)(svs + n);
    unsigned* binned = (unsigned*)(csr + (size_t)nbk * ecap);
    float*    xs     = (float*)(binned + (size_t)nbk * ecap);
    int*      cut16  = (int*)(xs + (size_t)n * 8);
    __half*   g1h    = (__half*)binned;

    const int B = 256;
    const int nchunk = (E + CHUNK - 1) / CHUNK;
    const int gridW  = ((size_t)n * 64 + B - 1) / B;        // wave per node

    k_binit  <<<1, 512, 0, stream>>>(bcur, ecap);
    k_bin    <<<nchunk, 256, 0, stream>>>(src, dst, bcur, binned, E);
    k_sort   <<<nbk, 256, 0, stream>>>(binned, bcur, x, rpN, rpE, csr, dis, xs, n, ecap);
    k_layer1 <<<gridW, B, 0, stream>>>(rpN, rpE, csr, cut16, xs, dis, W1, b1, g1h, n);
    k_layer23<<<L23_BLOCKS, L23_TPB, 0, stream>>>(rpN, rpE, cut16, csr, g1h, dis, W2, b2, W3, svs, n);
    k_out    <<<gridW, B, 0, stream>>>(rpN, rpE, csr, svs, dis, b3, out, n);
}

// Round 7
// 481.089 us; speedup vs baseline: 1.3154x; 1.3154x over previous
//
#include <hip/hip_runtime.h>
#include <hip/hip_fp16.h>

#define NFEAT 5
#define HID 64
#define BSH 8               // dst bucket = dst >> 8  (256 nodes/bucket)
#define BNODES 256
#define NBK2 512            // max buckets (n <= 131072)
#define CHUNK 4096          // edges per bin block
#define ECAPMAX 12288       // per-bucket slice cap (LDS rank array bound)

// persistent layer23 phase-sweep geometry (spill-free envelope)
#define L23_BLOCKS 1024
#define L23_TPB 256
#define L23_WAVES (L23_BLOCKS * L23_TPB / 64)   // 4096 waves, 4 blocks/CU co-resident
#define NPW 26                                  // nodes per wave (covers 106496), even for pairing
#define NPH 4                                   // src phases
#define PHW2 25600                              // src window = 3.1 MB of g1h (fits 4MB XCD L2)

// ---- init per-bucket allocator cursors to static bases ----
__global__ void k_binit(int* bcur, int ecap) {
    bcur[threadIdx.x] = threadIdx.x * ecap;
}

// ---- bin edges by dst-bucket into statically-capped bucket slices.
//      packed 4B entries: src | (dst&255)<<17 ; ONE LDS-atomic round; int4 loads ----
__global__ __launch_bounds__(256) void
k_bin(const int* __restrict__ src, const int* __restrict__ dst,
      int* bcur, unsigned* __restrict__ binned, int E) {
    __shared__ unsigned stg[CHUNK];          // 16 KB
    __shared__ unsigned short bkt[CHUNK];    // 8 KB
    __shared__ int hist[NBK2], base[NBK2], gb[NBK2];
    __shared__ int tmp[256];
    int t = threadIdx.x;
    int e0 = blockIdx.x * CHUNK;
    int cc = E - e0; if (cc > CHUNK) cc = CHUNK;
    hist[t] = 0; hist[t + 256] = 0;
    __syncthreads();
    unsigned me[16]; int mb[16]; unsigned short mr[16];
    const int4* src4 = (const int4*)(src + e0);
    const int4* dst4 = (const int4*)(dst + e0);
#pragma unroll
    for (int k = 0; k < 4; ++k) {
        int i4 = k * 256 + t;          // int4 index within chunk
        int ib = i4 * 4;               // edge offset within chunk
        int ss[4], dd[4];
        bool any = false;
        if (e0 + ib + 3 < E) {
            int4 s4 = src4[i4], d4 = dst4[i4];
            ss[0]=s4.x; ss[1]=s4.y; ss[2]=s4.z; ss[3]=s4.w;
            dd[0]=d4.x; dd[1]=d4.y; dd[2]=d4.z; dd[3]=d4.w;
            any = true;
#pragma unroll
            for (int j = 0; j < 4; ++j) mb[k*4+j] = 0;
        } else {
#pragma unroll
            for (int j = 0; j < 4; ++j) {
                if (e0 + ib + j < E) { ss[j]=src[e0+ib+j]; dd[j]=dst[e0+ib+j]; any=true; mb[k*4+j]=0; }
                else mb[k*4+j] = -1;
            }
        }
        if (any) {
#pragma unroll
            for (int j = 0; j < 4; ++j) {
                int idx = k * 4 + j;
                if (mb[idx] >= 0) {
                    mb[idx] = dd[j] >> BSH;
                    me[idx] = (unsigned)ss[j] | ((unsigned)(dd[j] & (BNODES - 1)) << 17);
                    mr[idx] = (unsigned short)atomicAdd(&hist[mb[idx]], 1);
                }
            }
        }
    }
    __syncthreads();
    // exclusive scan over 512 bins (2/thread)
    int c0 = hist[2*t], c1 = hist[2*t + 1];
    int s = c0 + c1;
    tmp[t] = s;
    __syncthreads();
    for (int off = 1; off < 256; off <<= 1) {
        int a = (t >= off) ? tmp[t - off] : 0;
        __syncthreads();
        tmp[t] += a;
        __syncthreads();
    }
    int excl = tmp[t] - s;
    base[2*t]     = excl;
    base[2*t + 1] = excl + c0;
    gb[2*t]     = c0 ? atomicAdd(&bcur[2*t], c0) : 0;
    gb[2*t + 1] = c1 ? atomicAdd(&bcur[2*t + 1], c1) : 0;
    __syncthreads();
#pragma unroll
    for (int k = 0; k < 16; ++k)
        if (mb[k] >= 0) {
            int p = base[mb[k]] + mr[k];
            stg[p] = me[k];
            bkt[p] = (unsigned short)mb[k];
        }
    __syncthreads();
#pragma unroll
    for (int k = 0; k < 16; ++k) {
        int p = k * 256 + t;
        if (p < cc) {
            int b = bkt[p];
            binned[gb[b] + (p - base[b])] = stg[p];   // coalesced bucket runs
        }
    }
}

// ---- per-bucket counting sort by local dst (node-major, contiguous rows):
//      pass-1 atomic returns final rank (LDS u16) -> pass-2 has NO atomics.
//      emits csr (padded layout), rpN/rpE, dis, xs = dis*x padded to 8 floats ----
__global__ __launch_bounds__(256) void
k_sort(const unsigned* __restrict__ binned, const int* __restrict__ bcur,
       const float* __restrict__ x, int* __restrict__ rpN, int* __restrict__ rpE,
       int* __restrict__ csr, float* __restrict__ dis, float* __restrict__ xs,
       int n, int ecap) {
    __shared__ unsigned short rank[ECAPMAX];   // 24 KB
    __shared__ int hist[BNODES];
    __shared__ int cur[BNODES];
    __shared__ int tmp[256];
    int t = threadIdx.x, b = blockIdx.x;
    int e0 = b * ecap;
    int cnt = bcur[b] - e0;           // edges in this bucket
    if (cnt > ecap) cnt = ecap;
    int v0 = b << BSH;
    int nv = n - v0; if (nv > BNODES) nv = BNODES;
    hist[t] = 0;
    __syncthreads();
    for (int i = t; i < cnt; i += 256) {
        int vl = binned[e0 + i] >> 17;
        rank[i] = (unsigned short)atomicAdd(&hist[vl], 1);
    }
    __syncthreads();
    // degree -> dis ; xs = dis * x (padded to 8 floats); one node/thread
    if (t < nv) {
        int v = v0 + t;
        float dv = rsqrtf((float)hist[t] + 1.0f);
        dis[v] = dv;
        const float* xr = x + (size_t)v * NFEAT;
        float* xw = xs + (size_t)v * 8;
        xw[0] = dv * xr[0]; xw[1] = dv * xr[1]; xw[2] = dv * xr[2];
        xw[3] = dv * xr[3]; xw[4] = dv * xr[4];
        xw[5] = 0.f; xw[6] = 0.f; xw[7] = 0.f;
    }
    // exclusive scan of 256 bins (1/thread)
    int c = hist[t];
    tmp[t] = c;
    __syncthreads();
    for (int off = 1; off < 256; off <<= 1) {
        int a = (t >= off) ? tmp[t - off] : 0;
        __syncthreads();
        tmp[t] += a;
        __syncthreads();
    }
    int excl = e0 + tmp[t] - c;       // absolute csr position
    cur[t] = excl;
    if (t < nv) { rpN[v0 + t] = excl; rpE[v0 + t] = excl + c; }
    __syncthreads();
    for (int i = t; i < cnt; i += 256) {
        unsigned e = binned[e0 + i];
        int vl = e >> 17;
        csr[cur[vl] + rank[i]] = (int)(e & 0x1FFFF);
    }
}

// ---- layer 1: wave/node + in-register bitonic src-sort of the row, PLUS
//      per-node phase-cut emission: cut16[ph-1][v] = absolute csr index of
//      first edge with src >= ph*PHW2 (ph=1..3). Phase 0 start = rpN,
//      phase 3 end = rpE. deg>64 rows: unsorted, all edges in last phase. ----
__global__ __launch_bounds__(256) void
k_layer1(const int* __restrict__ rpN, const int* __restrict__ rpE,
         int* __restrict__ csr, int* __restrict__ cut16,
         const float* __restrict__ xs, const float* __restrict__ dis,
         const float* __restrict__ W1, const float* __restrict__ b1,
         __half* __restrict__ g1h, int n) {
    int wave = (blockIdx.x * blockDim.x + threadIdx.x) >> 6;
    int lane = threadIdx.x & 63;
    if (wave >= n) return;
    int v = wave;
    int r0 = rpN[v], r1 = rpE[v];
    int cnt = r1 - r0;
    float a0 = 0.f, a1 = 0.f, a2 = 0.f, a3 = 0.f, a4 = 0.f;
    if (cnt <= 64) {
        int key = (lane < cnt) ? csr[r0 + lane] : 0x7FFFFFFF;
        // 64-lane bitonic sort (21 shfl_xor compare-exchange steps)
#pragma unroll
        for (int k = 2; k <= 64; k <<= 1) {
#pragma unroll
            for (int j = k >> 1; j > 0; j >>= 1) {
                int o = __shfl_xor(key, j, 64);
                bool keepmin = (((lane & j) == 0) == ((lane & k) == 0));
                int mn = key < o ? key : o;
                int mx = key > o ? key : o;
                key = keepmin ? mn : mx;
            }
        }
        // phase cuts: #edges with src < ph*PHW2 (sentinels excluded)
        int c1_ = __popcll(__ballot(key < 1 * PHW2));
        int c2_ = __popcll(__ballot(key < 2 * PHW2));
        int c3_ = __popcll(__ballot(key < 3 * PHW2));
        if (lane >= 1 && lane <= 3) {
            int cc = lane == 1 ? c1_ : lane == 2 ? c2_ : c3_;
            cut16[(lane - 1) * n + v] = r0 + cc;
        }
        if (lane < cnt) {
            csr[r0 + lane] = key;                 // persist sorted row
            const float4* q = (const float4*)(xs + (size_t)key * 8);
            float4 qa = q[0], qb = q[1];
            a0 = qa.x; a1 = qa.y; a2 = qa.z; a3 = qa.w; a4 = qb.x;
        }
    } else {
        if (lane >= 1 && lane <= 3) cut16[(lane - 1) * n + v] = r0;  // all in last phase
        for (int j = r0 + lane; j < r1; j += 64) {
            const float4* q = (const float4*)(xs + (size_t)csr[j] * 8);
            float4 qa = q[0], qb = q[1];
            a0 += qa.x; a1 += qa.y; a2 += qa.z; a3 += qa.w; a4 += qb.x;
        }
    }
#pragma unroll
    for (int m = 32; m > 0; m >>= 1) {
        a0 += __shfl_xor(a0, m, 64); a1 += __shfl_xor(a1, m, 64);
        a2 += __shfl_xor(a2, m, 64); a3 += __shfl_xor(a3, m, 64);
        a4 += __shfl_xor(a4, m, 64);
    }
    float dv = dis[v];
    const float* pv = xs + (size_t)v * 8;   // already dis[v]*x[v]
    a0 = dv * (a0 + pv[0]); a1 = dv * (a1 + pv[1]); a2 = dv * (a2 + pv[2]);
    a3 = dv * (a3 + pv[3]); a4 = dv * (a4 + pv[4]);
    int c = lane;
    float h = b1[c] + a0 * W1[c] + a1 * W1[64 + c] + a2 * W1[128 + c]
            + a3 * W1[192 + c] + a4 * W1[256 + c];
    g1h[(size_t)v * HID + c] = __float2half(dv * fmaxf(h, 0.0f));
}

// ---- layer 2+3: persistent phase-sweep gather, precomputed cuts, PAIRED rows.
//      1024 blocks x 256 thr (= 4 blocks/CU, ALL co-resident), bounds(256,4)
//      -> VGPR cap ~128, NO SPILL (r6 bug: bounds(256,8) forced 32 VGPR ->
//      acc/t spilled to scratch; WRITE_SIZE 404->2470 KB leak was the tell).
//      26 nodes/wave, 4 phases of 25600 srcs (3.1 MB g1h window, L2-fits).
//      Inner: node PAIRS issue two clamped groups-of-8 back-to-back ->
//      up to 16 independent g1h + 16 csr loads in flight (MLP compensates
//      the 4-wave/SIMD occupancy). All inner branches are wave-uniform
//      scalars (s_cbranch, no divergence). Plain csr loads (L2-cached;
//      r6's nontemporal forced HBM re-reads of the index stream). ----
__global__ __launch_bounds__(L23_TPB, 4) void
k_layer23(const int* __restrict__ rpN, const int* __restrict__ rpE,
          const int* __restrict__ cut16, const int* __restrict__ csr,
          const __half* __restrict__ g1h, const float* __restrict__ dis,
          const float* __restrict__ W2, const float* __restrict__ b2,
          const float* __restrict__ W3, float* __restrict__ svs, int n) {
    __shared__ float W2s[HID * HID];
    for (int i = threadIdx.x; i < HID * HID; i += L23_TPB) W2s[i] = W2[i];
    __syncthreads();
    int wv   = (blockIdx.x * L23_TPB + threadIdx.x) >> 6;
    int lane = threadIdx.x & 63;
    int v0 = wv * NPW;

    float acc[NPW];     // statically indexed only
#pragma unroll
    for (int i = 0; i < NPW; ++i) {
        int v = v0 + i;
        acc[i] = (v < n) ? __half2float(g1h[((size_t)v << 6) + lane]) : 0.f;  // self
    }

    for (int ph = 0; ph < NPH; ++ph) {
        // batch-load this wave's 26 window bounds (lanes 0..25), shfl-broadcast
        int sv_ = 0, ev_ = 0;
        int vL = v0 + lane;
        if (lane < NPW && vL < n) {
            sv_ = (ph == 0)       ? rpN[vL] : cut16[(ph - 1) * n + vL];
            ev_ = (ph == NPH - 1) ? rpE[vL] : cut16[ph * n + vL];
        }
#pragma unroll
        for (int i = 0; i < NPW; i += 2) {
            int a0 = __shfl(sv_, i, 64),     b0 = __shfl(ev_, i, 64);
            int a1 = __shfl(sv_, i + 1, 64), b1 = __shfl(ev_, i + 1, 64);
            int j0 = a0, j1 = a1;
            while (j0 < b0 || j1 < b1) {       // wave-uniform scalar condition
                float t0[8], t1[8];
                bool g0 = j0 < b0, g1v = j1 < b1;
                if (g0) {
#pragma unroll
                    for (int k = 0; k < 8; ++k) {
                        int idx = (j0 + k < b0) ? (j0 + k) : (b0 - 1);  // b0>j0>=a0 -> in-row
                        int s = csr[idx];
                        t0[k] = __half2float(g1h[((size_t)s << 6) + lane]);
                    }
                }
                if (g1v) {
#pragma unroll
                    for (int k = 0; k < 8; ++k) {
                        int idx = (j1 + k < b1) ? (j1 + k) : (b1 - 1);
                        int s = csr[idx];
                        t1[k] = __half2float(g1h[((size_t)s << 6) + lane]);
                    }
                }
                if (g0) {
#pragma unroll
                    for (int k = 0; k < 8; ++k) if (j0 + k < b0) acc[i] += t0[k];
                    j0 += 8;
                }
                if (g1v) {
#pragma unroll
                    for (int k = 0; k < 8; ++k) if (j1 + k < b1) acc[i + 1] += t1[k];
                    j1 += 8;
                }
            }
        }
    }

    // epilogue: W2 shfl-GEMM + relu + W3 dot per node
    for (int i = 0; i < NPW; ++i) {     // runtime loop; acc picked by select
        int v = v0 + i;
        if (v >= n) break;
        float a = acc[0];
#pragma unroll
        for (int t = 1; t < NPW; ++t) if (i == t) a = acc[t];
        float dv = dis[v];
        a *= dv;                                   // agg2[v, lane]
        float outv = b2[lane];
#pragma unroll
        for (int k = 0; k < HID; ++k)
            outv = fmaf(__shfl(a, k, 64), W2s[(k << 6) + lane], outv);
        outv = fmaxf(outv, 0.0f);
        float val = outv * W3[lane];
#pragma unroll
        for (int m = 32; m > 0; m >>= 1) val += __shfl_xor(val, m, 64);
        if (lane == 0) svs[v] = dv * val;          // pre-scaled for output gather
    }

    // safety tail (dead for n <= L23_WAVES*NPW = 106496)
    for (int v = L23_WAVES * NPW + wv; v < n; v += L23_WAVES) {
        int r0 = rpN[v], r1 = rpE[v];
        float a = __half2float(g1h[((size_t)v << 6) + lane]);
        for (int j = r0; j < r1; ++j)
            a += __half2float(g1h[((size_t)csr[j] << 6) + lane]);
        float dv = dis[v];
        a *= dv;
        float outv = b2[lane];
#pragma unroll
        for (int k = 0; k < HID; ++k)
            outv = fmaf(__shfl(a, k, 64), W2s[(k << 6) + lane], outv);
        outv = fmaxf(outv, 0.0f);
        float val = outv * W3[lane];
#pragma unroll
        for (int m = 32; m > 0; m >>= 1) val += __shfl_xor(val, m, 64);
        if (lane == 0) svs[v] = dv * val;
    }
}

// ---- output: wave/node scalar gather over contiguous row ----
__global__ __launch_bounds__(256) void
k_out(const int* __restrict__ rpN, const int* __restrict__ rpE,
      const int* __restrict__ csr, const float* __restrict__ svs,
      const float* __restrict__ dis, const float* __restrict__ b3,
      float* __restrict__ out, int n) {
    int wave = (blockIdx.x * blockDim.x + threadIdx.x) >> 6;
    int lane = threadIdx.x & 63;
    if (wave >= n) return;
    int v = wave;
    int r0 = rpN[v], r1 = rpE[v];
    float acc = (lane == 0) ? svs[v] : 0.f;        // self term
    for (int j = r0 + lane; j < r1; j += 64) acc += svs[csr[j]];
#pragma unroll
    for (int m = 32; m > 0; m >>= 1) acc += __shfl_xor(acc, m, 64);
    if (lane == 0) out[v] = b3[0] + dis[v] * acc;
}

extern "C" void kernel_launch(void* const* d_in, const int* in_sizes, int n_in,
                              void* d_out, int out_size, void* d_ws, size_t ws_size,
                              hipStream_t stream) {
    const float* x  = (const float*)d_in[0];
    const int*   ei = (const int*)d_in[1];
    const float* W1 = (const float*)d_in[2];
    const float* b1 = (const float*)d_in[3];
    const float* W2 = (const float*)d_in[4];
    const float* b2 = (const float*)d_in[5];
    const float* W3 = (const float*)d_in[6];
    const float* b3 = (const float*)d_in[7];
    float* out = (float*)d_out;

    const int n = out_size;           // 100000
    const int E = in_sizes[1] / 2;    // 3200000
    const int* src = ei;
    const int* dst = ei + E;

    const int nbk = (n + BNODES - 1) / BNODES;    // 391 buckets
    int ecap = E / nbk;
    ecap += ecap / 8 + 1024;                      // ~+25% headroom (>>20 sigma)
    if (ecap > ECAPMAX) ecap = ECAPMAX;

    // ws layout (int units):
    // bcur[512] | rpN[n] rpE[n] | dis[n] svs[n]
    // | csr[nbk*ecap] | binned[uint nbk*ecap] (g1h aliases binned) | xs[8n floats]
    // | cut16[3n ints]
    int*      bcur   = (int*)d_ws;
    int*      rpN    = bcur + 512;
    int*      rpE    = rpN + n;
    float*    dis    = (float*)(rpE + n);
    float*    svs    = dis + n;
    int*      csr    = (int*)(svs + n);
    unsigned* binned = (unsigned*)(csr + (size_t)nbk * ecap);
    float*    xs     = (float*)(binned + (size_t)nbk * ecap);
    int*      cut16  = (int*)(xs + (size_t)n * 8);
    __half*   g1h    = (__half*)binned;

    const int B = 256;
    const int nchunk = (E + CHUNK - 1) / CHUNK;
    const int gridW  = ((size_t)n * 64 + B - 1) / B;        // wave per node

    k_binit  <<<1, 512, 0, stream>>>(bcur, ecap);
    k_bin    <<<nchunk, 256, 0, stream>>>(src, dst, bcur, binned, E);
    k_sort   <<<nbk, 256, 0, stream>>>(binned, bcur, x, rpN, rpE, csr, dis, xs, n, ecap);
    k_layer1 <<<gridW, B, 0, stream>>>(rpN, rpE, csr, cut16, xs, dis, W1, b1, g1h, n);
    k_layer23<<<L23_BLOCKS, L23_TPB, 0, stream>>>(rpN, rpE, cut16, csr, g1h, dis, W2, b2, W3, svs, n);
    k_out    <<<gridW, B, 0, stream>>>(rpN, rpE, csr, svs, dis, b3, out, n);
}